// Round 5
// baseline (183.464 us; speedup 1.0000x reference)
//
#include <hip/hip_runtime.h>

// MPS layer, MFMA single-pass version, round 5.
// Math: M_s = x0*W0[s] + x1*W1[s] = s01*I + x0*D0[s] + x1*D1[s], D = W - I.
// Maintain T = (M_0...M_s)^T in MFMA accumulators:
//   T_new = s01*T (exact fp32 VALU) + D0^T*(x0*T)_bf16 + D1^T*(x1*T)_bf16.
//
// Layouts (v_mfma_f32_32x32x16_bf16, validated rounds 3-4, absmax 1.0):
//   A-operand: lane l holds row m=l&31, k = 8*(l>>5)+j (j=0..7)
//   B-operand: lane l holds col n=l&31, k = 8*(l>>5)+j
//   C/D:       lane l holds col  c=l&31, row = (reg&3)+8*(reg>>2)+4*(l>>5)
// acc->B conversion: per k-half q: v_permlane32_swap_b32 on reg pairs
// (q*8+r, q*8+4+r); then slot q*8+j = T[32t+16q+8*hi+j][col].
//
// Round 5 changes:
//  - make_dt: 256 blocks (64-row half-matrix each, 34KB LDS) — mystery probe:
//    if ~80us residue persists in total, it's harness-structural, not make_dt.
//  - chain: s-loop unrolled by 2 (ping-pong acc arrays, kills 64 movs/step),
//    permlane asm non-volatile (pure op -> scheduler can interleave),
//    compile-time LDS buffer index via template<CURB>.
//
// ws: res[2][128][128][128] f32 (16MB) | Dt (4MB bf16 fragment-major)
// Dt[mat][(ks*4+mt)*512 + l*8 + j] = W[mat][16ks+8(l>>5)+j][32mt+(l&31)] - I

typedef __attribute__((ext_vector_type(8))) short short8v;
typedef __attribute__((ext_vector_type(16))) float f32x16;

__device__ __forceinline__ unsigned cvt_pk_bf16(float lo, float hi) {
  unsigned r;
  asm("v_cvt_pk_bf16_f32 %0, %1, %2" : "=v"(r) : "v"(lo), "v"(hi));
  return r;
}

#define GLOAD_LDS16(g, l)                                          \
  __builtin_amdgcn_global_load_lds(                                \
      (const __attribute__((address_space(1))) void*)(g),          \
      (__attribute__((address_space(3))) void*)(l), 16, 0, 0)

// 256 blocks: block = (matrix, row-half). Stage 64x128 f32 to LDS (coalesced),
// gather A-fragments (conflict-free scalar reads), write coalesced 16B.
__global__ __launch_bounds__(256) void make_dt(const float* __restrict__ left,
                                               const float* __restrict__ right,
                                               ushort* __restrict__ Dt) {
  __shared__ float lw[64 * 132];
  const int tid = threadIdx.x;
  const int mat = blockIdx.x >> 1;   // side*64 + p*32 + s
  const int rh  = blockIdx.x & 1;    // row half: rows 64*rh .. 64*rh+63
  const float* W = (mat >= 64 ? right : left) + (size_t)(mat & 63) * 16384 +
                   (size_t)rh * 8192;

#pragma unroll
  for (int it = 0; it < 8; ++it) {
    int g = it * 256 + tid;  // float4 index in the 64x128 slab
    float4 v = *(const float4*)(W + g * 4);
    *(float4*)&lw[(g >> 5) * 132 + (g & 31) * 4] = v;
  }
  __syncthreads();

#pragma unroll
  for (int ff = 0; ff < 4; ++ff) {
    int f = ff * 256 + tid;             // frag slot within this half: 0..1023
    int l = f & 63, mt = (f >> 6) & 3, ksl = f >> 8;  // ksl = 0..3
    int m = 32 * mt + (l & 31);
    int kbl = 16 * ksl + 8 * (l >> 5);  // row offset within the 64-row half
    float v[8];
#pragma unroll
    for (int j = 0; j < 8; ++j)
      v[j] = lw[(kbl + j) * 132 + m] - ((64 * rh + kbl + j == m) ? 1.0f : 0.0f);
    uint4 o;
    o.x = cvt_pk_bf16(v[0], v[1]);
    o.y = cvt_pk_bf16(v[2], v[3]);
    o.z = cvt_pk_bf16(v[4], v[5]);
    o.w = cvt_pk_bf16(v[6], v[7]);
    *(uint4*)(Dt + (size_t)mat * 16384 +
              (size_t)(((4 * rh + ksl) * 4 + mt) * 64 + l) * 8) = o;
  }
}

// One chain step: aOut = s01*aIn + D0^T*(x0*aIn) + D1^T*(x1*aIn).
// Reads ldsD[CURB]; prefetches step s+1 into ldsD[CURB^1]; barrier at end.
// aIn is destroyed (permuted in place).
template <int CURB>
__device__ __forceinline__ void mps_step(int s, bool pf, const float* xs,
                                         const ushort* DtH,
                                         ushort (&ldsD)[2][32768],
                                         f32x16 (&aIn)[4], f32x16 (&aOut)[4],
                                         int lane, int wofs) {
  const float x0 = xs[2 * s], x1 = xs[2 * s + 1];
  const float s01 = x0 + x1;

  if (pf) {
#pragma unroll
    for (int p = 0; p < 2; ++p) {
      const ushort* gp = DtH + (size_t)(p * 32 + s + 1) * 16384;
#pragma unroll
      for (int i = 0; i < 8; ++i)
        GLOAD_LDS16(gp + i * 2048 + wofs + lane * 8,
                    &ldsD[CURB ^ 1][p * 16384 + i * 2048 + wofs]);
    }
  }

  // identity part (exact fp32)
#pragma unroll
  for (int t = 0; t < 4; ++t)
#pragma unroll
    for (int r = 0; r < 16; ++r) aOut[t][r] = s01 * aIn[t][r];

  // per k-slice: convert T -> scaled bf16 B-frags, then 16 MFMAs
#pragma unroll
  for (int ks = 0; ks < 8; ++ks) {
    const int t = ks >> 1, q = ks & 1;
#pragma unroll
    for (int r = 0; r < 4; ++r) {
      float a  = aIn[t][q * 8 + r];
      float b2 = aIn[t][q * 8 + 4 + r];
      asm("v_permlane32_swap_b32 %0, %1" : "+v"(a), "+v"(b2));
      aIn[t][q * 8 + r]     = a;   // T[32t+16q+8*hi+r][cg]
      aIn[t][q * 8 + 4 + r] = b2;  // T[32t+16q+8*hi+4+r][cg]
    }
    uint4 p0, p1;
    {
      const float* v = (const float*)&aIn[t] + q * 8;
      p0.x = cvt_pk_bf16(x0 * v[0], x0 * v[1]);
      p0.y = cvt_pk_bf16(x0 * v[2], x0 * v[3]);
      p0.z = cvt_pk_bf16(x0 * v[4], x0 * v[5]);
      p0.w = cvt_pk_bf16(x0 * v[6], x0 * v[7]);
      p1.x = cvt_pk_bf16(x1 * v[0], x1 * v[1]);
      p1.y = cvt_pk_bf16(x1 * v[2], x1 * v[3]);
      p1.z = cvt_pk_bf16(x1 * v[4], x1 * v[5]);
      p1.w = cvt_pk_bf16(x1 * v[6], x1 * v[7]);
    }
    const short8v y0 = __builtin_bit_cast(short8v, p0);
    const short8v y1 = __builtin_bit_cast(short8v, p1);
#pragma unroll
    for (int mt = 0; mt < 4; ++mt) {
      short8v d0 = *(const short8v*)&ldsD[CURB][(ks * 4 + mt) * 512 + lane * 8];
      short8v d1 =
          *(const short8v*)&ldsD[CURB][16384 + (ks * 4 + mt) * 512 + lane * 8];
      aOut[mt] = __builtin_amdgcn_mfma_f32_32x32x16_bf16(d0, y0, aOut[mt], 0, 0, 0);
      aOut[mt] = __builtin_amdgcn_mfma_f32_32x32x16_bf16(d1, y1, aOut[mt], 0, 0, 0);
    }
  }
  __syncthreads();  // buf[CURB] reads done by all waves; prefetch drained
}

__global__ __launch_bounds__(256, 1) void mps_chain_mfma(
    const float* __restrict__ inp, const float* __restrict__ left,
    const float* __restrict__ right, const ushort* __restrict__ Dt,
    float* __restrict__ res) {
  __shared__ ushort ldsD[2][32768];  // [buf][p*16384 + (ks*4+mt)*512 + lane*8]
  __shared__ float xs[64];

  const int tid  = threadIdx.x;
  const int half = blockIdx.x >> 7;
  const int b    = blockIdx.x & 127;
  const int lane = tid & 63;
  const int w    = tid >> 6;  // wave owns T cols 32w..32w+31
  const int c    = lane & 31;
  const int hi   = lane >> 5;
  const int cg   = 32 * w + c;
  const int wofs = w * 512;  // ushort offset of this wave's slice in a chunk

  if (tid < 64) xs[tid] = inp[b * 128 + half * 64 + tid];

  const ushort* DtH = Dt + (size_t)(half * 2) * 32 * 16384;  // p=0 slab

  __syncthreads();  // xs ready

  // stage s=1 into buf0 (latency hides under T0 init)
#pragma unroll
  for (int p = 0; p < 2; ++p) {
    const ushort* gp = DtH + (size_t)(p * 32 + 1) * 16384;
#pragma unroll
    for (int i = 0; i < 8; ++i)
      GLOAD_LDS16(gp + i * 2048 + wofs + lane * 8,
                  &ldsD[0][p * 16384 + i * 2048 + wofs]);
  }

  f32x16 A[4], B[4];  // ping-pong T accumulators

  // T_0 = M_0^T from W (fp32): T0[row][cg] = M0[cg][row]
  {
    const float* Wg = half ? right : left;
    const float x0 = xs[0], x1 = xs[1];
#pragma unroll
    for (int t = 0; t < 4; ++t)
#pragma unroll
      for (int g = 0; g < 4; ++g) {
        const int row = 32 * t + 8 * g + 4 * hi;
        const float4 w0 = *(const float4*)(Wg + cg * 128 + row);
        const float4 w1 = *(const float4*)(Wg + 32 * 16384 + cg * 128 + row);
        A[t][4 * g + 0] = x0 * w0.x + x1 * w1.x;
        A[t][4 * g + 1] = x0 * w0.y + x1 * w1.y;
        A[t][4 * g + 2] = x0 * w0.z + x1 * w1.z;
        A[t][4 * g + 3] = x0 * w0.w + x1 * w1.w;
      }
  }

  __syncthreads();  // drains vmcnt -> buf0 staged & visible

  // step s reads buf (s-1)&1. s=1: buf0 (A->B); pairs: even s buf1 (B->A),
  // odd s buf0 (A->B). 31 steps end in B.
  mps_step<0>(1, true, xs, DtH, ldsD, A, B, lane, wofs);
#pragma unroll 1
  for (int i = 0; i < 15; ++i) {
    mps_step<1>(2 + 2 * i, true, xs, DtH, ldsD, B, A, lane, wofs);
    mps_step<0>(3 + 2 * i, 3 + 2 * i < 31, xs, DtH, ldsD, A, B, lane, wofs);
  }

  // T[r][cg] = L[cg][r]: store row cg row-major
  float* O = res + (size_t)(half * 128 + b) * 16384;
#pragma unroll
  for (int t = 0; t < 4; ++t)
#pragma unroll
    for (int g = 0; g < 4; ++g) {
      const int row = 32 * t + 8 * g + 4 * hi;
      float4 o = {B[t][4 * g + 0], B[t][4 * g + 1], B[t][4 * g + 2],
                  B[t][4 * g + 3]};
      *(float4*)(O + cg * 128 + row) = o;
    }
}

#define TS 132  // padded LDS stride for the fp32 final kernel

__global__ __launch_bounds__(256) void mps_final(const float* __restrict__ res,
                                                 const float* __restrict__ middle,
                                                 float* __restrict__ out) {
  __shared__ float lA[128 * TS];  // R = res[1][b]
  __shared__ float lB[128 * TS];  // L = res[0][b]
  __shared__ float red[4][10];

  const int tid = threadIdx.x;
  const int b   = blockIdx.x;
  const float* Rg = res + (size_t)(128 + b) * 16384;
  const float* Lg = res + (size_t)b * 16384;

#pragma unroll
  for (int it = 0; it < 16; ++it) {
    int g = it * 256 + tid;
    int row = g >> 5, col = (g & 31) * 4;
    *(float4*)&lA[row * TS + col] = *(const float4*)(Rg + g * 4);
    *(float4*)&lB[row * TS + col] = *(const float4*)(Lg + g * 4);
  }
  __syncthreads();

  const int ty = tid >> 4, tx = tid & 15;
  const int k0 = ty * 8, j0 = tx * 8;

  float ct[8][8];
#pragma unroll
  for (int i = 0; i < 8; ++i)
#pragma unroll
    for (int j = 0; j < 8; ++j) ct[i][j] = 0.f;

  for (int k = 0; k < 128; k += 4) {
    float4 a[8];
#pragma unroll
    for (int i = 0; i < 8; ++i)
      a[i] = *(const float4*)&lA[(k0 + i) * TS + k];
    float4 b0[4], b1[4];
#pragma unroll
    for (int kk = 0; kk < 4; ++kk) {
      b0[kk] = *(const float4*)&lB[(k + kk) * TS + j0];
      b1[kk] = *(const float4*)&lB[(k + kk) * TS + j0 + 4];
    }
#pragma unroll
    for (int i = 0; i < 8; ++i) {
      const float av[4] = {a[i].x, a[i].y, a[i].z, a[i].w};
#pragma unroll
      for (int kk = 0; kk < 4; ++kk) {
        const float aa = av[kk];
        ct[i][0] = fmaf(aa, b0[kk].x, ct[i][0]);
        ct[i][1] = fmaf(aa, b0[kk].y, ct[i][1]);
        ct[i][2] = fmaf(aa, b0[kk].z, ct[i][2]);
        ct[i][3] = fmaf(aa, b0[kk].w, ct[i][3]);
        ct[i][4] = fmaf(aa, b1[kk].x, ct[i][4]);
        ct[i][5] = fmaf(aa, b1[kk].y, ct[i][5]);
        ct[i][6] = fmaf(aa, b1[kk].z, ct[i][6]);
        ct[i][7] = fmaf(aa, b1[kk].w, ct[i][7]);
      }
    }
  }
  // ct[i][jj] = (R@L)[k0+i][j0+jj];  out[b,c] = sum mid[c][j][k] * P[k][j]
#pragma unroll
  for (int cc = 0; cc < 10; ++cc) {
    const float* m = middle + cc * 16384;
    float accv = 0.f;
#pragma unroll
    for (int jj = 0; jj < 8; ++jj) {
      const float* mr = m + (j0 + jj) * 128 + k0;
      float4 m0 = *(const float4*)(mr);
      float4 m1 = *(const float4*)(mr + 4);
      accv += m0.x * ct[0][jj] + m0.y * ct[1][jj] + m0.z * ct[2][jj] + m0.w * ct[3][jj];
      accv += m1.x * ct[4][jj] + m1.y * ct[5][jj] + m1.z * ct[6][jj] + m1.w * ct[7][jj];
    }
    float v = accv;
#pragma unroll
    for (int off = 32; off > 0; off >>= 1) v += __shfl_down(v, off);
    if ((tid & 63) == 0) red[tid >> 6][cc] = v;
  }
  __syncthreads();
  if (tid < 10)
    out[b * 10 + tid] = red[0][tid] + red[1][tid] + red[2][tid] + red[3][tid];
}

extern "C" void kernel_launch(void* const* d_in, const int* in_sizes, int n_in,
                              void* d_out, int out_size, void* d_ws, size_t ws_size,
                              hipStream_t stream) {
  const float* inputs = (const float*)d_in[0];  // (128, 64, 2)
  const float* left   = (const float*)d_in[1];  // (2, 32, 128, 128)
  const float* right  = (const float*)d_in[2];  // (2, 32, 128, 128)
  const float* middle = (const float*)d_in[3];  // (10, 128, 128)
  float* out = (float*)d_out;                   // (128, 10)

  float*  res = (float*)d_ws;                                       // 16 MB
  ushort* Dt  = (ushort*)((char*)d_ws + (size_t)16 * 1024 * 1024);  // 4 MB

  make_dt<<<256, 256, 0, stream>>>(left, right, Dt);
  mps_chain_mfma<<<256, 256, 0, stream>>>(inputs, left, right, Dt, res);
  mps_final<<<128, 256, 0, stream>>>(res, middle, out);
}

// Round 8
// 181.400 us; speedup vs baseline: 1.0114x; 1.0114x over previous
//
#include <hip/hip_runtime.h>

// MPS layer, round 8: r4-exact chain (known-good: 93us, absmax 1.0) +
// DOUBLE make_dt launch as a DVFS-ramp probe.
//
// Accounting across rounds: dur_us = sum of kernel durations (r2 matches
// exactly). make_dt measures ~69-81us for ~12MB traffic across THREE
// different implementations -> not code. Hypothesis: first-dispatch DVFS
// ramp absorbed by whatever runs first (r2: hidden in 510us chain).
// Probe: run make_dt twice (idempotent). Ramp => mk2 ~3us, total ~182.
// Internal pathology => mk2 ~80us, total ~260.
//
// Math: M_s = x0*W0[s] + x1*W1[s] = s01*I + x0*D0[s] + x1*D1[s], D = W - I.
// Maintain T = (M_0...M_s)^T in MFMA accumulators:
//   T_new = s01*T (exact fp32 VALU) + D0^T*(x0*T)_bf16 + D1^T*(x1*T)_bf16.
//
// Layouts (v_mfma_f32_32x32x16_bf16, validated rounds 3-5, absmax 1.0):
//   A-operand: lane l holds row m=l&31, k = 8*(l>>5)+j (j=0..7)
//   B-operand: lane l holds col n=l&31, k = 8*(l>>5)+j
//   C/D:       lane l holds col  c=l&31, row = (reg&3)+8*(reg>>2)+4*(l>>5)
// acc->B conversion per k-half q: v_permlane32_swap_b32 on reg pairs
// (q*8+r, q*8+4+r); then slot q*8+j = T[32t+16q+8*hi+j][col].
//
// ws: res[2][128][128][128] f32 (16MB) | Dt (4MB bf16 fragment-major)
// Dt[mat][(ks*4+mt)*512 + l*8 + j] = W[mat][16ks+8(l>>5)+j][32mt+(l&31)] - I

typedef __attribute__((ext_vector_type(8))) short short8v;
typedef __attribute__((ext_vector_type(16))) float f32x16;

__device__ __forceinline__ unsigned cvt_pk_bf16(float lo, float hi) {
  unsigned r;
  asm("v_cvt_pk_bf16_f32 %0, %1, %2" : "=v"(r) : "v"(lo), "v"(hi));
  return r;
}

#define GLOAD_LDS16(g, l)                                          \
  __builtin_amdgcn_global_load_lds(                                \
      (const __attribute__((address_space(1))) void*)(g),          \
      (__attribute__((address_space(3))) void*)(l), 16, 0, 0)

// 256 blocks: block = (matrix, row-half). Stage 64x128 f32 to LDS (coalesced),
// gather A-fragments (conflict-free scalar reads), write coalesced 16B.
__global__ __launch_bounds__(256) void make_dt(const float* __restrict__ left,
                                               const float* __restrict__ right,
                                               ushort* __restrict__ Dt) {
  __shared__ float lw[64 * 132];
  const int tid = threadIdx.x;
  const int mat = blockIdx.x >> 1;   // side*64 + p*32 + s
  const int rh  = blockIdx.x & 1;    // rows 64*rh .. 64*rh+63
  const float* W = (mat >= 64 ? right : left) + (size_t)(mat & 63) * 16384 +
                   (size_t)rh * 8192;

#pragma unroll
  for (int it = 0; it < 8; ++it) {
    int g = it * 256 + tid;
    float4 v = *(const float4*)(W + g * 4);
    *(float4*)&lw[(g >> 5) * 132 + (g & 31) * 4] = v;
  }
  __syncthreads();

#pragma unroll
  for (int ff = 0; ff < 4; ++ff) {
    int f = ff * 256 + tid;             // frag slot within this half: 0..1023
    int l = f & 63, mt = (f >> 6) & 3, ksl = f >> 8;
    int m = 32 * mt + (l & 31);
    int kbl = 16 * ksl + 8 * (l >> 5);
    float v[8];
#pragma unroll
    for (int j = 0; j < 8; ++j)
      v[j] = lw[(kbl + j) * 132 + m] - ((64 * rh + kbl + j == m) ? 1.0f : 0.0f);
    uint4 o;
    o.x = cvt_pk_bf16(v[0], v[1]);
    o.y = cvt_pk_bf16(v[2], v[3]);
    o.z = cvt_pk_bf16(v[4], v[5]);
    o.w = cvt_pk_bf16(v[6], v[7]);
    *(uint4*)(Dt + (size_t)mat * 16384 +
              (size_t)(((4 * rh + ksl) * 4 + mt) * 64 + l) * 8) = o;
  }
}

__global__ __launch_bounds__(256, 1) void mps_chain_mfma(
    const float* __restrict__ inp, const float* __restrict__ left,
    const float* __restrict__ right, const ushort* __restrict__ Dt,
    float* __restrict__ res) {
  __shared__ ushort ldsD[2][32768];  // [buf][p*16384 + (ks*4+mt)*512 + lane*8]
  __shared__ float xs[64];

  const int tid  = threadIdx.x;
  const int half = blockIdx.x >> 7;
  const int b    = blockIdx.x & 127;
  const int lane = tid & 63;
  const int w    = tid >> 6;  // wave owns T cols 32w..32w+31
  const int c    = lane & 31;
  const int hi   = lane >> 5;
  const int cg   = 32 * w + c;
  const int wofs = w * 512;  // ushort offset of this wave's slice in a chunk

  if (tid < 64) xs[tid] = inp[b * 128 + half * 64 + tid];

  const ushort* DtH = Dt + (size_t)(half * 2) * 32 * 16384;  // p=0 slab

  __syncthreads();  // xs ready

  // stage s=1 into buf0 (latency hides under T0 init)
#pragma unroll
  for (int p = 0; p < 2; ++p) {
    const ushort* gp = DtH + (size_t)(p * 32 + 1) * 16384;
#pragma unroll
    for (int i = 0; i < 8; ++i)
      GLOAD_LDS16(gp + i * 2048 + wofs + lane * 8,
                  &ldsD[0][p * 16384 + i * 2048 + wofs]);
  }

  f32x16 acc[4];

  // T_0 = M_0^T from W (fp32): T0[row][cg] = M0[cg][row]
  {
    const float* Wg = half ? right : left;
    const float x0 = xs[0], x1 = xs[1];
#pragma unroll
    for (int t = 0; t < 4; ++t)
#pragma unroll
      for (int g = 0; g < 4; ++g) {
        const int row = 32 * t + 8 * g + 4 * hi;
        const float4 w0 = *(const float4*)(Wg + cg * 128 + row);
        const float4 w1 = *(const float4*)(Wg + 32 * 16384 + cg * 128 + row);
        acc[t][4 * g + 0] = x0 * w0.x + x1 * w1.x;
        acc[t][4 * g + 1] = x0 * w0.y + x1 * w1.y;
        acc[t][4 * g + 2] = x0 * w0.z + x1 * w1.z;
        acc[t][4 * g + 3] = x0 * w0.w + x1 * w1.w;
      }
  }

  __syncthreads();  // drains vmcnt -> buf0 staged & visible

  int cur = 0;
  for (int s = 1; s < 32; ++s) {
    const float x0 = xs[2 * s], x1 = xs[2 * s + 1];
    const float s01 = x0 + x1;

    if (s < 31) {
#pragma unroll
      for (int p = 0; p < 2; ++p) {
        const ushort* gp = DtH + (size_t)(p * 32 + s + 1) * 16384;
#pragma unroll
        for (int i = 0; i < 8; ++i)
          GLOAD_LDS16(gp + i * 2048 + wofs + lane * 8,
                      &ldsD[cur ^ 1][p * 16384 + i * 2048 + wofs]);
      }
    }

    f32x16 tn[4];
#pragma unroll
    for (int t = 0; t < 4; ++t)
#pragma unroll
      for (int r = 0; r < 16; ++r) tn[t][r] = s01 * acc[t][r];

#pragma unroll
    for (int ks = 0; ks < 8; ++ks) {
      const int t = ks >> 1, q = ks & 1;
#pragma unroll
      for (int r = 0; r < 4; ++r) {
        float a  = acc[t][q * 8 + r];
        float b2 = acc[t][q * 8 + 4 + r];
        asm volatile("v_permlane32_swap_b32 %0, %1" : "+v"(a), "+v"(b2));
        acc[t][q * 8 + r]     = a;   // T[32t+16q+8*hi+r][cg]
        acc[t][q * 8 + 4 + r] = b2;  // T[32t+16q+8*hi+4+r][cg]
      }
      uint4 p0, p1;
      {
        const float* v = (const float*)&acc[t] + q * 8;
        p0.x = cvt_pk_bf16(x0 * v[0], x0 * v[1]);
        p0.y = cvt_pk_bf16(x0 * v[2], x0 * v[3]);
        p0.z = cvt_pk_bf16(x0 * v[4], x0 * v[5]);
        p0.w = cvt_pk_bf16(x0 * v[6], x0 * v[7]);
        p1.x = cvt_pk_bf16(x1 * v[0], x1 * v[1]);
        p1.y = cvt_pk_bf16(x1 * v[2], x1 * v[3]);
        p1.z = cvt_pk_bf16(x1 * v[4], x1 * v[5]);
        p1.w = cvt_pk_bf16(x1 * v[6], x1 * v[7]);
      }
      const short8v y0 = __builtin_bit_cast(short8v, p0);
      const short8v y1 = __builtin_bit_cast(short8v, p1);
#pragma unroll
      for (int mt = 0; mt < 4; ++mt) {
        short8v d0 = *(const short8v*)&ldsD[cur][(ks * 4 + mt) * 512 + lane * 8];
        short8v d1 = *(const short8v*)&ldsD[cur][16384 + (ks * 4 + mt) * 512 + lane * 8];
        tn[mt] = __builtin_amdgcn_mfma_f32_32x32x16_bf16(d0, y0, tn[mt], 0, 0, 0);
        tn[mt] = __builtin_amdgcn_mfma_f32_32x32x16_bf16(d1, y1, tn[mt], 0, 0, 0);
      }
    }

#pragma unroll
    for (int t = 0; t < 4; ++t) acc[t] = tn[t];
    __syncthreads();
    cur ^= 1;
  }

  // T[r][cg] = L[cg][r]: store row cg row-major
  float* O = res + (size_t)(half * 128 + b) * 16384;
#pragma unroll
  for (int t = 0; t < 4; ++t)
#pragma unroll
    for (int g = 0; g < 4; ++g) {
      const int row = 32 * t + 8 * g + 4 * hi;
      float4 o = {acc[t][4 * g + 0], acc[t][4 * g + 1], acc[t][4 * g + 2],
                  acc[t][4 * g + 3]};
      *(float4*)(O + cg * 128 + row) = o;
    }
}

#define TS 132  // padded LDS stride for the fp32 final kernel

__global__ __launch_bounds__(256) void mps_final(const float* __restrict__ res,
                                                 const float* __restrict__ middle,
                                                 float* __restrict__ out) {
  __shared__ float lA[128 * TS];  // R = res[1][b]
  __shared__ float lB[128 * TS];  // L = res[0][b]
  __shared__ float red[4][10];

  const int tid = threadIdx.x;
  const int b   = blockIdx.x;
  const float* Rg = res + (size_t)(128 + b) * 16384;
  const float* Lg = res + (size_t)b * 16384;

#pragma unroll
  for (int it = 0; it < 16; ++it) {
    int g = it * 256 + tid;
    int row = g >> 5, col = (g & 31) * 4;
    *(float4*)&lA[row * TS + col] = *(const float4*)(Rg + g * 4);
    *(float4*)&lB[row * TS + col] = *(const float4*)(Lg + g * 4);
  }
  __syncthreads();

  const int ty = tid >> 4, tx = tid & 15;
  const int k0 = ty * 8, j0 = tx * 8;

  float ct[8][8];
#pragma unroll
  for (int i = 0; i < 8; ++i)
#pragma unroll
    for (int j = 0; j < 8; ++j) ct[i][j] = 0.f;

  for (int k = 0; k < 128; k += 4) {
    float4 a[8];
#pragma unroll
    for (int i = 0; i < 8; ++i)
      a[i] = *(const float4*)&lA[(k0 + i) * TS + k];
    float4 b0[4], b1[4];
#pragma unroll
    for (int kk = 0; kk < 4; ++kk) {
      b0[kk] = *(const float4*)&lB[(k + kk) * TS + j0];
      b1[kk] = *(const float4*)&lB[(k + kk) * TS + j0 + 4];
    }
#pragma unroll
    for (int i = 0; i < 8; ++i) {
      const float av[4] = {a[i].x, a[i].y, a[i].z, a[i].w};
#pragma unroll
      for (int kk = 0; kk < 4; ++kk) {
        const float aa = av[kk];
        ct[i][0] = fmaf(aa, b0[kk].x, ct[i][0]);
        ct[i][1] = fmaf(aa, b0[kk].y, ct[i][1]);
        ct[i][2] = fmaf(aa, b0[kk].z, ct[i][2]);
        ct[i][3] = fmaf(aa, b0[kk].w, ct[i][3]);
        ct[i][4] = fmaf(aa, b1[kk].x, ct[i][4]);
        ct[i][5] = fmaf(aa, b1[kk].y, ct[i][5]);
        ct[i][6] = fmaf(aa, b1[kk].z, ct[i][6]);
        ct[i][7] = fmaf(aa, b1[kk].w, ct[i][7]);
      }
    }
  }
  // ct[i][jj] = (R@L)[k0+i][j0+jj];  out[b,c] = sum mid[c][j][k] * P[k][j]
#pragma unroll
  for (int cc = 0; cc < 10; ++cc) {
    const float* m = middle + cc * 16384;
    float accv = 0.f;
#pragma unroll
    for (int jj = 0; jj < 8; ++jj) {
      const float* mr = m + (j0 + jj) * 128 + k0;
      float4 m0 = *(const float4*)(mr);
      float4 m1 = *(const float4*)(mr + 4);
      accv += m0.x * ct[0][jj] + m0.y * ct[1][jj] + m0.z * ct[2][jj] + m0.w * ct[3][jj];
      accv += m1.x * ct[4][jj] + m1.y * ct[5][jj] + m1.z * ct[6][jj] + m1.w * ct[7][jj];
    }
    float v = accv;
#pragma unroll
    for (int off = 32; off > 0; off >>= 1) v += __shfl_down(v, off);
    if ((tid & 63) == 0) red[tid >> 6][cc] = v;
  }
  __syncthreads();
  if (tid < 10)
    out[b * 10 + tid] = red[0][tid] + red[1][tid] + red[2][tid] + red[3][tid];
}

extern "C" void kernel_launch(void* const* d_in, const int* in_sizes, int n_in,
                              void* d_out, int out_size, void* d_ws, size_t ws_size,
                              hipStream_t stream) {
  const float* inputs = (const float*)d_in[0];  // (128, 64, 2)
  const float* left   = (const float*)d_in[1];  // (2, 32, 128, 128)
  const float* right  = (const float*)d_in[2];  // (2, 32, 128, 128)
  const float* middle = (const float*)d_in[3];  // (10, 128, 128)
  float* out = (float*)d_out;                   // (128, 10)

  float*  res = (float*)d_ws;                                       // 16 MB
  ushort* Dt  = (ushort*)((char*)d_ws + (size_t)16 * 1024 * 1024);  // 4 MB

  // DVFS-ramp probe: launch make_dt twice (idempotent). If the ~80us ghost
  // is a first-dispatch clock ramp, the second instance runs at ~3us and
  // total stays ~182us; if it's internal to make_dt, total jumps to ~260us.
  make_dt<<<256, 256, 0, stream>>>(left, right, Dt);
  make_dt<<<256, 256, 0, stream>>>(left, right, Dt);
  mps_chain_mfma<<<256, 256, 0, stream>>>(inputs, left, right, Dt, res);
  mps_final<<<128, 256, 0, stream>>>(res, middle, out);
}